// Round 5
// baseline (61.138 us; speedup 1.0000x reference)
//
#include <hip/hip_runtime.h>

// Problem constants (from reference): B=4096, N_IN=64, N_OUT=64, M=4096.
#define BATCH 4096
#define NIN   64
#define NOUT  64
#define M_TOT (NIN * NOUT)

// ---------------------------------------------------------------------------
// Kernel 1: build WM from (aW, uW, tW). One thread per m = j*64 + k.
// Transposed layout for coalesced main-kernel loads:
//   WT[(j*3 + q)*64 + k] = row q of matrix (j,k)  (quad = (Rq0,Rq1,Rq2,tq))
// bottom row [0,0,0,1] implicit. 192 KiB in d_ws.
// ---------------------------------------------------------------------------
__global__ __launch_bounds__(256) void build_wm_kernel(
    const float* __restrict__ aW, const float* __restrict__ uW,
    const float* __restrict__ tW, float4* __restrict__ WT) {
  int m = blockIdx.x * 256 + threadIdx.x;
  if (m >= M_TOT) return;
  int j = m >> 6, k = m & 63;

  float a  = aW[m];
  float ux = 1.f / (1.f + expf(-uW[3 * m + 0]));
  float uy = 1.f / (1.f + expf(-uW[3 * m + 1]));
  float uz = 1.f / (1.f + expf(-uW[3 * m + 2]));
  float inv = 1.f / sqrtf(ux * ux + uy * uy + uz * uz);
  ux *= inv; uy *= inv; uz *= inv;

  float sa = sinf(a), ca = cosf(a);
  float xx = ux * ux, yy = uy * uy, zz = uz * uz;
  float xy = ux * uy, xz = ux * uz, yz = uy * uz;

  float R00 = ca * (1.f - xx) + xx;
  float R01 = -sa * uz + ca * (-xy) + xy;
  float R02 =  sa * uy + ca * (-xz) + xz;
  float R10 =  sa * uz + ca * (-xy) + xy;
  float R11 = ca * (1.f - yy) + yy;
  float R12 = -sa * ux + ca * (-yz) + yz;
  float R20 = -sa * uy + ca * (-xz) + xz;
  float R21 =  sa * ux + ca * (-yz) + yz;
  float R22 = ca * (1.f - zz) + zz;

  float t0 = tW[3 * m + 0], t1 = tW[3 * m + 1], t2 = tW[3 * m + 2];

  WT[(j * 3 + 0) * 64 + k] = make_float4(R00, R01, R02, t0);
  WT[(j * 3 + 1) * 64 + k] = make_float4(R10, R11, R12, t1);
  WT[(j * 3 + 2) * 64 + k] = make_float4(R20, R21, R22, t2);
}

// ---------------------------------------------------------------------------
// Kernel 2: chain product, 2-way split over j via associativity.
// Block = 128 threads = 2 waves, one batch row b = blockIdx.x:
//   wave 0: j in [0,32)  -> P0       wave 1: j in [32,64) -> P1
// lane = k. I loads via wave-uniform scalar pointer (s_load -> SGPRs).
// W loads lane-coalesced (1 KiB/instr), L2-resident. O = P0 @ P1 via LDS.
// Grid 4096 blocks, 4.4KB LDS -> up to 16 blocks/CU resident with backlog
// (round-3's 2048x256 had exactly 8 blocks/CU, zero slack, occupancy 43%).
// Branch-free register prefetch of j+1's W quads (peeled first/last iter).
// NO register cap (round-2's (256,8) forced VGPR=32 -> 200MB scratch spill).
// ---------------------------------------------------------------------------

// generic: write A-row (4 dests) from I-row r and affine W rows W0..W2
#define IMUL_TO(D0, D1, D2, D3, r, W0, W1, W2)                       \
  D0 = r.x * W0.x + r.y * W1.x + r.z * W2.x;                         \
  D1 = r.x * W0.y + r.y * W1.y + r.z * W2.y;                         \
  D2 = r.x * W0.z + r.y * W1.z + r.z * W2.z;                         \
  D3 = r.x * W0.w + r.y * W1.w + r.z * W2.w + r.w;

#define CMUL_ROW(x)                                                            \
  {                                                                            \
    float t0 = c[x*4+0]*A00 + c[x*4+1]*A10 + c[x*4+2]*A20 + c[x*4+3]*A30;      \
    float t1 = c[x*4+0]*A01 + c[x*4+1]*A11 + c[x*4+2]*A21 + c[x*4+3]*A31;      \
    float t2 = c[x*4+0]*A02 + c[x*4+1]*A12 + c[x*4+2]*A22 + c[x*4+3]*A32;      \
    float t3 = c[x*4+0]*A03 + c[x*4+1]*A13 + c[x*4+2]*A23 + c[x*4+3]*A33;      \
    c[x*4+0] = t0; c[x*4+1] = t1; c[x*4+2] = t2; c[x*4+3] = t3;                \
  }

// compute A = I[j] @ W(W0,W1,W2) and fold into carry c
#define STEP_FOLD(JJ, W0, W1, W2)                                              \
  {                                                                            \
    float4 r0 = Ib[(JJ) * 4 + 0], r1 = Ib[(JJ) * 4 + 1];                       \
    float4 r2 = Ib[(JJ) * 4 + 2], r3 = Ib[(JJ) * 4 + 3];                       \
    float A00, A01, A02, A03, A10, A11, A12, A13;                              \
    float A20, A21, A22, A23, A30, A31, A32, A33;                              \
    IMUL_TO(A00, A01, A02, A03, r0, W0, W1, W2)                                \
    IMUL_TO(A10, A11, A12, A13, r1, W0, W1, W2)                                \
    IMUL_TO(A20, A21, A22, A23, r2, W0, W1, W2)                                \
    IMUL_TO(A30, A31, A32, A33, r3, W0, W1, W2)                                \
    CMUL_ROW(0) CMUL_ROW(1) CMUL_ROW(2) CMUL_ROW(3)                            \
  }

__global__ __launch_bounds__(128) void chain_kernel(
    const float4* __restrict__ I4, const float4* __restrict__ WT,
    float4* __restrict__ O4) {
  const int lane = threadIdx.x & 63;
  const int half = threadIdx.x >> 6;  // 0: j in [0,32), 1: j in [32,64)
  const int b    = (int)blockIdx.x;

  // wave-uniform scalar I base -> s_load, rows live in SGPRs
  const int ioff = __builtin_amdgcn_readfirstlane((b * NIN + half * 32) * 4);
  const float4* __restrict__ Ib = I4 + ioff;
  const float4* __restrict__ Wb = WT + (size_t)(half * 32 * 3) * 64 + lane;

  float c[16];
  float4 w0n, w1n, w2n;

  {  // peeled j=0: c = A directly (skip identity multiply), prefetch j=1
    float4 w0 = Wb[0], w1 = Wb[64], w2 = Wb[128];
    const float4* wp = Wb + 192;
    w0n = wp[0]; w1n = wp[64]; w2n = wp[128];

    float4 r0 = Ib[0], r1 = Ib[1], r2 = Ib[2], r3 = Ib[3];
    IMUL_TO(c[0],  c[1],  c[2],  c[3],  r0, w0, w1, w2)
    IMUL_TO(c[4],  c[5],  c[6],  c[7],  r1, w0, w1, w2)
    IMUL_TO(c[8],  c[9],  c[10], c[11], r2, w0, w1, w2)
    IMUL_TO(c[12], c[13], c[14], c[15], r3, w0, w1, w2)
  }

#pragma unroll 2
  for (int j = 1; j < 31; ++j) {
    // rotate: current = prefetched; prefetch j+1 (branch-free)
    float4 w0 = w0n, w1 = w1n, w2 = w2n;
    const float4* wp = Wb + (size_t)(j + 1) * 192;
    w0n = wp[0]; w1n = wp[64]; w2n = wp[128];
    STEP_FOLD(j, w0, w1, w2)
  }

  // peeled j=31: no prefetch
  STEP_FOLD(31, w0n, w1n, w2n)

  // combine: O = P0 @ P1
  __shared__ float P[64][17];  // padded stride 17 -> conflict-free
  if (half == 1) {
#pragma unroll
    for (int i = 0; i < 16; i++) P[lane][i] = c[i];
  }
  __syncthreads();
  if (half == 0) {
    float A00 = P[lane][0],  A01 = P[lane][1];
    float A02 = P[lane][2],  A03 = P[lane][3];
    float A10 = P[lane][4],  A11 = P[lane][5];
    float A12 = P[lane][6],  A13 = P[lane][7];
    float A20 = P[lane][8],  A21 = P[lane][9];
    float A22 = P[lane][10], A23 = P[lane][11];
    float A30 = P[lane][12], A31 = P[lane][13];
    float A32 = P[lane][14], A33 = P[lane][15];

    CMUL_ROW(0)
    CMUL_ROW(1)
    CMUL_ROW(2)
    CMUL_ROW(3)

    float4* o = O4 + ((size_t)b * NOUT + lane) * 4;
    o[0] = make_float4(c[0],  c[1],  c[2],  c[3]);
    o[1] = make_float4(c[4],  c[5],  c[6],  c[7]);
    o[2] = make_float4(c[8],  c[9],  c[10], c[11]);
    o[3] = make_float4(c[12], c[13], c[14], c[15]);
  }
}

extern "C" void kernel_launch(void* const* d_in, const int* in_sizes, int n_in,
                              void* d_out, int out_size, void* d_ws, size_t ws_size,
                              hipStream_t stream) {
  const float* I  = (const float*)d_in[0];
  const float* aW = (const float*)d_in[1];
  const float* uW = (const float*)d_in[2];
  const float* tW = (const float*)d_in[3];

  float4* WT = (float4*)d_ws;  // 192 KiB scratch for transposed WM

  build_wm_kernel<<<M_TOT / 256, 256, 0, stream>>>(aW, uW, tW, WT);
  chain_kernel<<<BATCH, 128, 0, stream>>>((const float4*)I, WT, (float4*)d_out);
}